// Round 7
// baseline (391.621 us; speedup 1.0000x reference)
//
#include <hip/hip_runtime.h>

// ComHG graph attention: N=50000, E=1.6M, DIN=128, DOUT=256, DA=32
// Round 7: software-pipeline node_kernel (depth-2: prefetch pk + a_colh
// fragments across the accumulate phase) to kill the serial
// pk->gather->dot->accumulate dependency chain (R6: VALU 39% / HBM 46%,
// latency-bound). gemm widened to 32 rows/block (halves Wx streaming).
// Pipeline:
//   memset bcnt[nb]
//   K1 proj:   a_row(f32) = x@W_row*rsqrt(DA); a_colh = bf16(x@W_col); xh = bf16(x)
//   K2 bhist:  LDS-hist coarse buckets (row>>7), flush to bcnt
//   K3 bscan:  bstart = excl prefix(bcnt); bcursor = bstart       (1 block)
//   K4 part:   per 2048-edge block: LDS hist -> reserve sub-ranges in bcursor
//              -> write ibuf{rowlocal<<16|col, adj} in contiguous runs
//   K5 csr:    per bucket: LDS count[128]+scan -> off[] and pk{col,adj}
//   K6 node:   wave-per-node fused logits+softmax+SpMM, pipelined, bf16 gathers
//   K7 gemm:   out = feat @ W_x + b_x  (32 rows/block)
// (global-max shift dropped: cancels in p/deg up to 1e-15 eps; absmax 0.0625 ok)

#define DIN   128
#define DOUT  256
#define DA    32
#define SLOPE 0.2f
#define RSQRT_DA 0.17677669529663687f   // 1/sqrt(32)
#define BSH   7                         // 128 nodes per coarse bucket
#define NBMAX 512                       // LDS sizing; nb = ceil(n/128) = 391
#define BH_CHUNK 4096
#define PB_CHUNK 2048

typedef unsigned int uint;
typedef unsigned short ushort;

static __device__ __forceinline__ ushort f2bf(float f) {
  const uint u = __float_as_uint(f);
  return (ushort)((u + 0x7fffu + ((u >> 16) & 1u)) >> 16);
}

// ---------------- K1: projections + bf16 copies ----------------
__global__ __launch_bounds__(256) void proj_kernel(
    const float* __restrict__ x, const float* __restrict__ Wr,
    const float* __restrict__ Wc, float* __restrict__ a_row,
    ushort* __restrict__ a_colh, ushort* __restrict__ xh) {
  __shared__ float sWr[DIN][DA];
  __shared__ float sWc[DIN][DA];
  __shared__ float sx[8][DIN];
  const int t = threadIdx.x;
  {
    const float4* wr4 = (const float4*)Wr;
    const float4* wc4 = (const float4*)Wc;
    float4* sr4 = (float4*)sWr;
    float4* sc4 = (float4*)sWc;
#pragma unroll
    for (int i = 0; i < 4; ++i) {
      sr4[t + 256 * i] = wr4[t + 256 * i];
      sc4[t + 256 * i] = wc4[t + 256 * i];
    }
  }
  const int node0 = blockIdx.x * 8;
  {
    const float4* xg = (const float4*)(x + (size_t)node0 * DIN);
    const float4 v = xg[t];
    ((float4*)sx)[t] = v;
    ushort4 h;
    h.x = f2bf(v.x); h.y = f2bf(v.y); h.z = f2bf(v.z); h.w = f2bf(v.w);
    ((ushort4*)(xh + (size_t)node0 * DIN))[t] = h;
  }
  __syncthreads();

  const int node = t >> 5;
  const int da = t & 31;
  float ar = 0.f, ac = 0.f;
#pragma unroll
  for (int k = 0; k < DIN; ++k) {
    const float xv = sx[node][k];
    ar += xv * sWr[k][da];
    ac += xv * sWc[k][da];
  }
  const int g = (node0 + node) * DA + da;
  a_row[g] = ar * RSQRT_DA;
  a_colh[g] = f2bf(ac);
}

// ---------------- K2: coarse bucket histogram (LDS-staged) ----------------
__global__ __launch_bounds__(256) void bhist_kernel(
    const int* __restrict__ row, int* __restrict__ bcnt, int nb, int E) {
  __shared__ int hist[NBMAX];
  const int t = threadIdx.x;
  for (int b = t; b < nb; b += 256) hist[b] = 0;
  __syncthreads();
  const int e0 = blockIdx.x * BH_CHUNK;
#pragma unroll
  for (int u = 0; u < BH_CHUNK / 256; ++u) {
    const int e = e0 + u * 256 + t;
    if (e < E) atomicAdd(&hist[row[e] >> BSH], 1);
  }
  __syncthreads();
  for (int b = t; b < nb; b += 256) {
    const int c = hist[b];
    if (c) atomicAdd(&bcnt[b], c);
  }
}

// ---------------- K3: single-block scan over nb buckets ----------------
__global__ __launch_bounds__(512) void bscan_kernel(
    const int* __restrict__ bcnt, int* __restrict__ bstart,
    int* __restrict__ bcursor, int nb) {
  __shared__ int s[512];
  const int t = threadIdx.x;
  const int v = (t < nb) ? bcnt[t] : 0;
  s[t] = v;
  __syncthreads();
  for (int ofs = 1; ofs < 512; ofs <<= 1) {
    const int tmp = (t >= ofs) ? s[t - ofs] : 0;
    __syncthreads();
    s[t] += tmp;
    __syncthreads();
  }
  if (t < nb) {
    const int ex = s[t] - v;
    bstart[t] = ex;
    bcursor[t] = ex;
  }
  if (t == nb) bstart[nb] = s[nb - 1];   // == E
}

// ---------------- K4: partition into coarse buckets ----------------
__global__ __launch_bounds__(256) void part_kernel(
    const int* __restrict__ row, const int* __restrict__ col,
    const float* __restrict__ adj, int* __restrict__ bcursor,
    int2* __restrict__ ibuf, int nb, int E) {
  __shared__ int hist[NBMAX];
  __shared__ int base[NBMAX];
  const int t = threadIdx.x;
  const int e0 = blockIdx.x * PB_CHUNK;
  for (int b = t; b < nb; b += 256) hist[b] = 0;
  __syncthreads();
  int myrow[PB_CHUNK / 256];
#pragma unroll
  for (int u = 0; u < PB_CHUNK / 256; ++u) {
    const int e = e0 + u * 256 + t;
    myrow[u] = (e < E) ? row[e] : -1;
    if (myrow[u] >= 0) atomicAdd(&hist[myrow[u] >> BSH], 1);
  }
  __syncthreads();
  for (int b = t; b < nb; b += 256) {
    const int c = hist[b];
    base[b] = c ? atomicAdd(&bcursor[b], c) : 0;
    hist[b] = 0;   // reuse as intra-block rank counter
  }
  __syncthreads();
#pragma unroll
  for (int u = 0; u < PB_CHUNK / 256; ++u) {
    const int e = e0 + u * 256 + t;
    if (e < E) {
      const int r = myrow[u];
      const int b = r >> BSH;
      const int pos = base[b] + atomicAdd(&hist[b], 1);
      ibuf[pos] = make_int2(((r & 127) << 16) | col[e], __float_as_int(adj[e]));
    }
  }
}

// ---------------- K5: bucket-local CSR build (off + pk) ----------------
__global__ __launch_bounds__(256) void csr_kernel(
    const int* __restrict__ bstart, const int2* __restrict__ ibuf,
    int* __restrict__ off, int2* __restrict__ pk, int n, int E) {
  __shared__ int cnt[128];
  __shared__ int excl[128];
  const int b = blockIdx.x;
  const int t = threadIdx.x;
  const int estart = bstart[b];
  const int eend = bstart[b + 1];
  if (t < 128) cnt[t] = 0;
  __syncthreads();
  for (int e = estart + t; e < eend; e += 256)
    atomicAdd(&cnt[ibuf[e].x >> 16], 1);
  __syncthreads();
  if (t < 128) excl[t] = cnt[t];
  __syncthreads();
  for (int ofs = 1; ofs < 128; ofs <<= 1) {
    const int v = (t < 128 && t >= ofs) ? excl[t - ofs] : 0;
    __syncthreads();
    if (t < 128) excl[t] += v;
    __syncthreads();
  }
  if (t < 128) excl[t] -= cnt[t];
  __syncthreads();
  const int node0 = b << BSH;
  if (t < 128 && node0 + t < n) off[node0 + t] = estart + excl[t];
  if (b == gridDim.x - 1 && t == 0) off[n] = E;
  if (t < 128) cnt[t] = 0;
  __syncthreads();
  for (int e = estart + t; e < eend; e += 256) {
    const int2 v = ibuf[e];
    const int rl = v.x >> 16;
    const int pos = estart + excl[rl] + atomicAdd(&cnt[rl], 1);
    pk[pos] = make_int2(v.x & 0xffff, v.y);
  }
}

// ---------------- K6: wave-per-node fused SpMM, software-pipelined ----------------
// Per iteration k: issue pk[k+1] -> accumulate chunk k-1 (covers in-flight
// a_colh frags q0..q3 of chunk k and pk prefetch) -> dot/exp chunk k -> issue
// a_colh gather for chunk k+1. Same-wave LDS ordering => no barriers.
__global__ __launch_bounds__(256) void node_kernel(
    const uint* __restrict__ xh, const float* __restrict__ a_row,
    const ushort* __restrict__ a_colh, const int* __restrict__ off,
    const int2* __restrict__ pk, float* __restrict__ feat, int n) {
  __shared__ int2  spk[4][64];
  __shared__ float sp[4][64];
  __shared__ float s_ar[4][DA];
  const int t = threadIdx.x;
  const int w = t >> 6;
  const int lane = t & 63;
  const int i = blockIdx.x * 4 + w;
  if (i >= n) return;
  if (lane < DA) s_ar[w][lane] = a_row[(size_t)i * DA + lane];
  const int off0 = off[i];
  const int off1 = off[i + 1];
  float aax = 0.f, aay = 0.f, apx = 0.f, apy = 0.f, deg = 0.f;

  const int ne = off1 - off0;
  if (ne > 0) {
    const int nch = (ne + 63) >> 6;
    int idx = off0 + lane;
    if (idx >= off1) idx = off1 - 1;          // clamp: in-bounds, unused lanes
    int2 e_cur = pk[idx];
    uint4 q0, q1, q2, q3;
    {
      const uint4* ac = (const uint4*)(a_colh + (size_t)e_cur.x * DA);
      q0 = ac[0]; q1 = ac[1]; q2 = ac[2]; q3 = ac[3];
    }
    int m_prev = 0;   // in-loop: 0 or 64 (only last chunk is partial)
    for (int k = 0; k < nch; ++k) {
      const int base = off0 + (k << 6);
      const int m_cur = min(64, off1 - base);
      int2 e_nxt;
      if (k + 1 < nch) {
        int idx2 = base + 64 + lane;
        if (idx2 >= off1) idx2 = off1 - 1;
        e_nxt = pk[idx2];                      // prefetch (covered below)
      }
      // accumulate chunk k-1 from LDS (the long phase)
      for (int j = 0; j < m_prev; j += 8) {
#pragma unroll
        for (int u = 0; u < 8; ++u) {
          const int2 e = spk[w][j + u];
          const float pv = sp[w][j + u];
          const uint xv = xh[(size_t)e.x * 64 + lane];
          const float fx = __uint_as_float(xv << 16);
          const float fy = __uint_as_float(xv & 0xffff0000u);
          const float av = __int_as_float(e.y);
          aax += av * fx; aay += av * fy;
          apx += pv * fx; apy += pv * fy;
          deg += pv;
        }
      }
      // dot/exp for chunk k (q* arrived during accumulate)
      {
        const float* ar = s_ar[w];
        float dot =
          __uint_as_float(q0.x << 16) * ar[0] + __uint_as_float(q0.x & 0xffff0000u) * ar[1] +
          __uint_as_float(q0.y << 16) * ar[2] + __uint_as_float(q0.y & 0xffff0000u) * ar[3] +
          __uint_as_float(q0.z << 16) * ar[4] + __uint_as_float(q0.z & 0xffff0000u) * ar[5] +
          __uint_as_float(q0.w << 16) * ar[6] + __uint_as_float(q0.w & 0xffff0000u) * ar[7] +
          __uint_as_float(q1.x << 16) * ar[8] + __uint_as_float(q1.x & 0xffff0000u) * ar[9] +
          __uint_as_float(q1.y << 16) * ar[10] + __uint_as_float(q1.y & 0xffff0000u) * ar[11] +
          __uint_as_float(q1.z << 16) * ar[12] + __uint_as_float(q1.z & 0xffff0000u) * ar[13] +
          __uint_as_float(q1.w << 16) * ar[14] + __uint_as_float(q1.w & 0xffff0000u) * ar[15] +
          __uint_as_float(q2.x << 16) * ar[16] + __uint_as_float(q2.x & 0xffff0000u) * ar[17] +
          __uint_as_float(q2.y << 16) * ar[18] + __uint_as_float(q2.y & 0xffff0000u) * ar[19] +
          __uint_as_float(q2.z << 16) * ar[20] + __uint_as_float(q2.z & 0xffff0000u) * ar[21] +
          __uint_as_float(q2.w << 16) * ar[22] + __uint_as_float(q2.w & 0xffff0000u) * ar[23] +
          __uint_as_float(q3.x << 16) * ar[24] + __uint_as_float(q3.x & 0xffff0000u) * ar[25] +
          __uint_as_float(q3.y << 16) * ar[26] + __uint_as_float(q3.y & 0xffff0000u) * ar[27] +
          __uint_as_float(q3.z << 16) * ar[28] + __uint_as_float(q3.z & 0xffff0000u) * ar[29] +
          __uint_as_float(q3.w << 16) * ar[30] + __uint_as_float(q3.w & 0xffff0000u) * ar[31];
        const float l = (dot >= 0.f) ? dot : SLOPE * dot;
        sp[w][lane] = __expf(l);
        spk[w][lane] = e_cur;
      }
      if (k + 1 < nch) {
        e_cur = e_nxt;
        const uint4* ac = (const uint4*)(a_colh + (size_t)e_cur.x * DA);
        q0 = ac[0]; q1 = ac[1]; q2 = ac[2]; q3 = ac[3];   // covered by next accumulate
      }
      m_prev = m_cur;
    }
    // epilogue: accumulate last chunk
    int j = 0;
    for (; j + 8 <= m_prev; j += 8) {
#pragma unroll
      for (int u = 0; u < 8; ++u) {
        const int2 e = spk[w][j + u];
        const float pv = sp[w][j + u];
        const uint xv = xh[(size_t)e.x * 64 + lane];
        const float fx = __uint_as_float(xv << 16);
        const float fy = __uint_as_float(xv & 0xffff0000u);
        const float av = __int_as_float(e.y);
        aax += av * fx; aay += av * fy;
        apx += pv * fx; apy += pv * fy;
        deg += pv;
      }
    }
    for (; j < m_prev; ++j) {
      const int2 e = spk[w][j];
      const float pv = sp[w][j];
      const uint xv = xh[(size_t)e.x * 64 + lane];
      const float fx = __uint_as_float(xv << 16);
      const float fy = __uint_as_float(xv & 0xffff0000u);
      const float av = __int_as_float(e.y);
      aax += av * fx; aay += av * fy;
      apx += pv * fx; apy += pv * fy;
      deg += pv;
    }
  }
  const float inv = 0.5f / (deg + 1e-15f);
  ((float2*)feat)[(size_t)i * 64 + lane] =
      make_float2(0.5f * aax + inv * apx, 0.5f * aay + inv * apy);
}

// ---------------- K7: dense GEMM out = feat @ W_x + b (32 rows/block) ----------------
__global__ __launch_bounds__(256) void gemm_kernel(
    const float* __restrict__ feat, const float* __restrict__ Wx,
    const float* __restrict__ bx, float* __restrict__ out, int n) {
  __shared__ float fs[32][DIN];   // 16 KB
  const int t = threadIdx.x;
  const int row0 = blockIdx.x * 32;
  const int rows = min(32, n - row0);
  {
    const float4* fg = (const float4*)(feat + (size_t)row0 * DIN);
    float4* fs4 = (float4*)fs;
    const int tot = rows * (DIN / 4);
    for (int idx = t; idx < tot; idx += 256) fs4[idx] = fg[idx];
  }
  __syncthreads();

  float acc[32];
#pragma unroll
  for (int r = 0; r < 32; ++r) acc[r] = 0.f;

  for (int k = 0; k < DIN; k += 4) {
    const float w0 = Wx[(k + 0) * DOUT + t];
    const float w1 = Wx[(k + 1) * DOUT + t];
    const float w2 = Wx[(k + 2) * DOUT + t];
    const float w3 = Wx[(k + 3) * DOUT + t];
#pragma unroll
    for (int r = 0; r < 32; ++r) {
      const float4 f = *(const float4*)&fs[r][k];
      acc[r] += f.x * w0 + f.y * w1 + f.z * w2 + f.w * w3;
    }
  }

  const float b = bx[t];
  for (int r = 0; r < rows; ++r)
    out[(size_t)(row0 + r) * DOUT + t] = acc[r] + b;
}

extern "C" void kernel_launch(void* const* d_in, const int* in_sizes, int n_in,
                              void* d_out, int out_size, void* d_ws, size_t ws_size,
                              hipStream_t stream) {
  const float* x   = (const float*)d_in[0];
  const int*   row = (const int*)d_in[1];
  const int*   col = (const int*)d_in[2];
  const float* adj = (const float*)d_in[3];
  const float* Wr  = (const float*)d_in[4];
  const float* Wc  = (const float*)d_in[5];
  const float* Wx  = (const float*)d_in[6];
  const float* bx  = (const float*)d_in[7];
  float* out = (float*)d_out;

  const int n = in_sizes[0] / DIN;   // 50000
  const int E = in_sizes[1];         // 1600000
  const int nb = (n + 127) >> BSH;   // 391 coarse buckets

  // Workspace (ibuf overlaid on feat: disjoint lifetimes)
  int* w4 = (int*)d_ws;
  float* a_row   = (float*)w4;  w4 += (size_t)n * DA;        // 6.4 MB
  float* feat    = (float*)w4;  w4 += (size_t)n * DIN;       // 25.6 MB
  int2*  ibuf    = (int2*)feat;                              // overlay (12.8 MB)
  int*   off     = w4;          w4 += n + 1;
  int*   bcnt    = w4;          w4 += nb;                    // zeroed
  int*   bstart  = w4;          w4 += nb + 1;
  int*   bcursor = w4;          w4 += nb;
  w4 = (int*)(((uintptr_t)w4 + 15) & ~(uintptr_t)15);
  ushort* a_colh = (ushort*)w4; w4 += (size_t)n * DA / 2;    // 3.2 MB
  uint*   xh     = (uint*)w4;   w4 += (size_t)n * DIN / 2;   // 12.8 MB
  int2*   pk     = (int2*)w4;                                // 12.8 MB
  // total ~= 61 MB

  hipMemsetAsync(bcnt, 0, (size_t)nb * sizeof(int), stream);

  proj_kernel<<<n / 8, 256, 0, stream>>>(x, Wr, Wc, a_row, a_colh, (ushort*)xh);
  bhist_kernel<<<(E + BH_CHUNK - 1) / BH_CHUNK, 256, 0, stream>>>(row, bcnt, nb, E);
  bscan_kernel<<<1, 512, 0, stream>>>(bcnt, bstart, bcursor, nb);
  part_kernel<<<(E + PB_CHUNK - 1) / PB_CHUNK, 256, 0, stream>>>(
      row, col, adj, bcursor, ibuf, nb, E);
  csr_kernel<<<nb, 256, 0, stream>>>(bstart, ibuf, off, pk, n, E);
  node_kernel<<<(n + 3) / 4, 256, 0, stream>>>(xh, a_row, a_colh, off, pk, feat, n);
  gemm_kernel<<<(n + 31) / 32, 256, 0, stream>>>(feat, Wx, bx, out, n);
}